// Round 13
// baseline (284.185 us; speedup 1.0000x reference)
//
#include <hip/hip_runtime.h>
#include <hip/hip_bf16.h>

// TrittentionCube on MI355X. B=1, P=256, D=512, N=8, H=64. Round 23:
//  - Base = round 19 exact (best, 244.9 us); tri_attn FROZEN at r19 form
//    (r22's 8-wave variant regressed: occupancy 2x but dur 65->78; chain
//    model falsified -- tri_attn is at its structural floor).
//  - KEY: in_npz_mb=21.85 == fp32 sizes -> harness runs the fp32 paths.
//  - WK pre-convert fp32->bf16, riding FREE on proj_all's dispatch (24 extra
//    grid-z rows = 96 blocks, idle CUs during proj's 160-block run), into
//    dead-until-tri_attn Sbuf head. s1t_all now always-bf16 body: 16B vector
//    B-loads replace {2x float4 + 8 cvt}/frag. Numerically IDENTICAL (the
//    fp32 s1t path already rounded WK via __float2bfloat16).
//  - zred folded into gemm_all (A-staging sums ks fp32 partials inline;
//    proven identical-absmax in r20). 6 -> 5 dispatches.

typedef __hip_bfloat16 bf16;
typedef __attribute__((ext_vector_type(8))) short short8;
typedef __attribute__((ext_vector_type(4))) short s16x4;
typedef __attribute__((ext_vector_type(4))) float floatx4;

__device__ __forceinline__ float ldf(const float* p){ return *p; }
__device__ __forceinline__ float ldf(const bf16* p){ return __bfloat162float(*p); }
__device__ __forceinline__ void  stf(float* p, float v){ *p = v; }
__device__ __forceinline__ void  stf(bf16*  p, float v){ *p = __float2bfloat16(v); }

__device__ __forceinline__ floatx4 mfma16(short8 a, short8 b, floatx4 c){
  return __builtin_amdgcn_mfma_f32_16x16x32_bf16(a, b, c, 0, 0, 0);
}
__device__ __forceinline__ short8 ld_g8(const bf16* p){
  return *reinterpret_cast<const short8*>(p);
}
__device__ __forceinline__ short bfs(float x){
  bf16 v = __float2bfloat16(x);
  return *reinterpret_cast<short*>(&v);
}

// Vectorized 4-elem load -> fp32 (G13: no scalar bf16 staging).
__device__ __forceinline__ void ld4(const bf16* p, float* o){
  s16x4 v = *reinterpret_cast<const s16x4*>(p);
  #pragma unroll
  for (int i = 0; i < 4; i++)
    o[i] = __uint_as_float(((unsigned)(unsigned short)v[i]) << 16);
}
__device__ __forceinline__ void ld4(const float* p, float* o){
  float4 v = *reinterpret_cast<const float4*>(p);
  o[0] = v.x; o[1] = v.y; o[2] = v.z; o[3] = v.w;
}

// Wave-uniform dtype detect: threshold 40/64, >7 sigma from both dtypes.
__device__ __forceinline__ bool is_bf16_x(const void* xv)
{
  const unsigned* x32 = (const unsigned*)xv;
  unsigned w = x32[threadIdx.x & 63];
  unsigned lo = w & 0xFFFFu;
  unsigned e  = (lo >> 7) & 0xFFu;
  bool v = (lo == 0u) || (e >= 90u && e <= 145u);
  unsigned long long m = __ballot(v);
  return __popcll(m) >= 40;
}

// ---------------- proj_all (r19 body) + WK-convert rider (bz>=40) -----------
template<typename TI>
__device__ __forceinline__ void proj_body(
    const TI* __restrict__ x, const TI* const* Ws, const TI* const* bs,
    bf16* __restrict__ tproj, float* As, float* Bs)
{
  const int bz = blockIdx.z, j = bz >> 3, n = bz & 7;
  const TI* B    = Ws[j] + (size_t)n * 32768;
  const TI* bias = bs[j] + n * 64;
  bf16* out = tproj + (size_t)j * 131072;
  const int m0 = blockIdx.y * 64;
  const int t = threadIdx.x, tx = t & 15, ty = t >> 4;
  float acc[4][4] = {};
  for (int k0 = 0; k0 < 512; k0 += 16) {
    { int m = t >> 2, kk = (t & 3) * 4;
      float a[4]; ld4(x + (size_t)(m0 + m) * 512 + (k0 + kk), a);
      As[(kk+0)*68+m] = a[0]; As[(kk+1)*68+m] = a[1];
      As[(kk+2)*68+m] = a[2]; As[(kk+3)*68+m] = a[3]; }
    { int kk = t >> 4, nn = (t & 15) * 4;
      float b[4]; ld4(B + (size_t)(k0 + kk) * 64 + nn, b);
      Bs[kk*68+nn+0] = b[0]; Bs[kk*68+nn+1] = b[1];
      Bs[kk*68+nn+2] = b[2]; Bs[kk*68+nn+3] = b[3]; }
    __syncthreads();
    #pragma unroll
    for (int kk = 0; kk < 16; kk++) {
      float4 a4 = *reinterpret_cast<const float4*>(&As[kk*68 + ty*4]);
      float4 b4 = *reinterpret_cast<const float4*>(&Bs[kk*68 + tx*4]);
      float av[4] = {a4.x,a4.y,a4.z,a4.w}, bv[4] = {b4.x,b4.y,b4.z,b4.w};
      #pragma unroll
      for (int im = 0; im < 4; im++)
        #pragma unroll
        for (int in = 0; in < 4; in++) acc[im][in] += av[im] * bv[in];
    }
    __syncthreads();
  }
  #pragma unroll
  for (int im = 0; im < 4; im++)
    #pragma unroll
    for (int in = 0; in < 4; in++) {
      float v = acc[im][in] + ldf(bias + tx*4 + in);
      int p = m0 + ty*4 + im, h = tx*4 + in;
      if (j < 3) out[(size_t)p * 512 + n*64 + h] = __float2bfloat16(v);
      else       out[(size_t)n * 16384 + (size_t)h * 256 + p] = __float2bfloat16(v);
    }
}

__global__ __launch_bounds__(256) void proj_all(
    const void* __restrict__ x,
    const void* W0, const void* b0, const void* W1, const void* b1,
    const void* W2, const void* b2, const void* W3, const void* b3,
    const void* W4, const void* b4, bf16* __restrict__ tproj,
    const void* __restrict__ WKf, bf16* __restrict__ wkbf)
{
  __shared__ float As[16*68];
  __shared__ float Bs[16*68];
  const int bz = blockIdx.z;
  if (bz >= 40) {
    // WK fp32 -> bf16 rider: 96 blocks (bz 40..63 x y 0..3), grid-stride x8.
    // Identical rounding to the old on-the-fly bfs path.
    if (is_bf16_x(x)) return;        // bf16 inputs: WK used directly
    const float* src = (const float*)WKf;
    const int cb = (bz - 40) * 4 + blockIdx.y;          // 0..95
    for (size_t i = ((size_t)cb*256 + threadIdx.x)*8; i < 2097152;
         i += (size_t)96*256*8) {
      float4 u0 = *reinterpret_cast<const float4*>(src + i);
      float4 u1 = *reinterpret_cast<const float4*>(src + i + 4);
      s16x4 lo = {bfs(u0.x), bfs(u0.y), bfs(u0.z), bfs(u0.w)};
      s16x4 hi = {bfs(u1.x), bfs(u1.y), bfs(u1.z), bfs(u1.w)};
      *reinterpret_cast<s16x4*>(wkbf + i)     = lo;
      *reinterpret_cast<s16x4*>(wkbf + i + 4) = hi;
    }
    return;
  }
  if (is_bf16_x(x)) {
    const bf16* Ws[5] = {(const bf16*)W0,(const bf16*)W1,(const bf16*)W2,
                         (const bf16*)W3,(const bf16*)W4};
    const bf16* bs[5] = {(const bf16*)b0,(const bf16*)b1,(const bf16*)b2,
                         (const bf16*)b3,(const bf16*)b4};
    proj_body<bf16>((const bf16*)x, Ws, bs, tproj, As, Bs);
  } else {
    const float* Ws[5] = {(const float*)W0,(const float*)W1,(const float*)W2,
                          (const float*)W3,(const float*)W4};
    const float* bs[5] = {(const float*)b0,(const float*)b1,(const float*)b2,
                          (const float*)b3,(const float*)b4};
    proj_body<float>((const float*)x, Ws, bs, tproj, As, Bs);
  }
}

// ---------------- s1t_all: always-bf16 s1t MFMA + tbs (grid y==4) -----------
__device__ __forceinline__ void s1t_body(
    const bf16* __restrict__ tc, const bf16* __restrict__ WK,
    bf16* __restrict__ s1t)
{
  const int i = blockIdx.x;
  const int t = threadIdx.x, wid = t >> 6, lane = t & 63, quad = lane >> 4, l16 = lane & 15;
  const int rw = blockIdx.y * 64 + wid * 16;
  floatx4 acc[4];
  #pragma unroll
  for (int jt = 0; jt < 4; jt++) acc[jt] = (floatx4){0.f, 0.f, 0.f, 0.f};
  for (int kc = 0; kc < 16; kc++) {
    short8 af = ld_g8(tc + (size_t)(rw + l16) * 512 + kc*32 + quad*8);
    const int n = kc >> 1, kk = (kc & 1) * 32 + quad * 8;
    #pragma unroll
    for (int jt = 0; jt < 4; jt++) {
      short8 bf = ld_g8(WK + ((size_t)(n*64 + i) * 64 + jt*16 + l16) * 64 + kk);
      acc[jt] = mfma16(af, bf, acc[jt]);
    }
  }
  #pragma unroll
  for (int jt = 0; jt < 4; jt++)
    #pragma unroll
    for (int reg = 0; reg < 4; reg++)
      s1t[(size_t)(rw + quad*4 + reg) * 4096 + i*64 + jt*16 + l16] =
          __float2bfloat16(acc[jt][reg]);
}

__global__ __launch_bounds__(256) void s1t_all(
    const void* __restrict__ x, const bf16* __restrict__ tb,
    const bf16* __restrict__ tc, const void* __restrict__ WK_orig,
    const bf16* __restrict__ wkbf,
    bf16* __restrict__ tbsbf, bf16* __restrict__ s1t)
{
  if (blockIdx.y == 4) {              // tbs: tbs[q][j] = (1/64)*sum_n tb[q][n][j]
    int t = blockIdx.x * 256 + threadIdx.x;
    int q = t >> 6, j = t & 63;
    float s = 0.f;
    #pragma unroll
    for (int n = 0; n < 8; n++) s += ldf(tb + q*512 + n*64 + j);
    tbsbf[t] = __float2bfloat16(s * 0.015625f);
    return;
  }
  const bf16* wk = is_bf16_x(x) ? (const bf16*)WK_orig : wkbf;
  s1t_body(tc, wk, s1t);
}

// ---------------- tri_attn (round-19 verbatim: pair-pipelined E->T) ---------
// LDS 44544 B: [0,34816) c [256][136 B] / Tt [64][528 B]; [34816,44032) Ew
// 2 bufs x [16][72 B] x4 waves; [44032,44544) scr.
#define E_PHASE(PT, BUF)                                                      \
  {                                                                           \
    const int ptb_ = ((PT)*4 + wid) * 16;                                     \
    for (int qt2 = 0; qt2 < 2; qt2++) {                                       \
      const int qh = qc + qt2*16;                                             \
      char* erow0 = (BUF) + (quad*4)*72 + (qt2*16 + l16)*2;                   \
      if (qh + 15 <= ptb_) {                                                  \
        for (int reg = 0; reg < 4; reg++)                                     \
          *reinterpret_cast<bf16*>(erow0 + reg*72) = __float2bfloat16(0.f);   \
      } else {                                                                \
        floatx4 acc = {0.f, 0.f, 0.f, 0.f};                                   \
        acc = mfma16(taf[PT][0], cfr[qt2][0], acc);                           \
        acc = mfma16(taf[PT][1], cfr[qt2][1], acc);                           \
        if (qh >= ptb_ + 16 && qh + 15 < r) {                                 \
          for (int reg = 0; reg < 4; reg++) {                                 \
            float e = __expf(acc[reg]);                                       \
            Zp += e;                                                          \
            *reinterpret_cast<bf16*>(erow0 + reg*72) = __float2bfloat16(e);   \
          }                                                                   \
        } else {                                                              \
          for (int reg = 0; reg < 4; reg++) {                                 \
            int p = ptb_ + quad*4 + reg;                                      \
            int q = qh + l16;                                                 \
            float e = (p < q && q < r) ? __expf(acc[reg]) : 0.f;              \
            Zp += e;                                                          \
            *reinterpret_cast<bf16*>(erow0 + reg*72) = __float2bfloat16(e);   \
          }                                                                   \
        }                                                                     \
      }                                                                       \
    }                                                                         \
  }

__global__ __launch_bounds__(256) void tri_attn(
    const bf16* __restrict__ ta,     // [p][n*64+h]
    const bf16* __restrict__ tbsbf,  // [q][64]
    const bf16* __restrict__ s1t,    // [r][i*64+j]
    const bf16* __restrict__ tdT,    // [n][h][p]
    const bf16* __restrict__ teT,    // [n][g][q]
    bf16* __restrict__ Sbuf)         // [n][r][h*64+g]
{
  __shared__ __align__(16) char smb[44544];
  const int bx = blockIdx.x;
  const int n = bx & 7;               // n -> XCD affinity
  const int r = 255 - (bx >> 3);      // big-r first
  const int t = threadIdx.x;
  const int wid = t >> 6, lane = t & 63, quad = lane >> 4, l16 = lane & 15;
  bf16* srow = Sbuf + (size_t)n * 1048576 + (size_t)r * 4096;
  if (r < 2) {                        // no valid (p<q<r): S' = 0
    short8 zz = (short8){0,0,0,0,0,0,0,0};
    reinterpret_cast<short8*>(srow)[t]       = zz;
    reinterpret_cast<short8*>(srow)[t + 256] = zz;
    return;
  }
  const int nch  = ((r - 1) >> 5) + 1;
  const int rcap = nch * 32;

  // ---- Phase 1: c[q][i] = tbs[q,:]·s1t[r][i,:]
  {
    const bf16* s1r = s1t + (size_t)r * 4096;
    short8 bfr[4][2];
    #pragma unroll
    for (int it = 0; it < 4; it++)
      #pragma unroll
      for (int kc = 0; kc < 2; kc++)
        bfr[it][kc] = ld_g8(s1r + (it*16 + l16)*64 + kc*32 + quad*8);
    #pragma unroll
    for (int qt = 0; qt < 4; qt++) {
      const int q0 = wid * 64 + qt * 16;
      if (q0 >= rcap) continue;
      if (q0 >= r) {
        #pragma unroll
        for (int it = 0; it < 4; it++)
          #pragma unroll
          for (int reg = 0; reg < 4; reg++) {
            int q = q0 + quad*4 + reg;
            *reinterpret_cast<bf16*>(smb + q*136 + (it*16 + l16)*2) =
                __float2bfloat16(0.f);
          }
        continue;
      }
      short8 af0 = ld_g8(tbsbf + (q0 + l16)*64 + quad*8);
      short8 af1 = ld_g8(tbsbf + (q0 + l16)*64 + 32 + quad*8);
      #pragma unroll
      for (int it = 0; it < 4; it++) {
        floatx4 acc = {0.f, 0.f, 0.f, 0.f};
        acc = mfma16(af0, bfr[it][0], acc);
        acc = mfma16(af1, bfr[it][1], acc);
        #pragma unroll
        for (int reg = 0; reg < 4; reg++) {
          int q = q0 + quad*4 + reg;
          float v = (q >= 1 && q < r) ? acc[reg] : 0.f;
          *reinterpret_cast<bf16*>(smb + q*136 + (it*16 + l16)*2) = __float2bfloat16(v);
        }
      }
    }
  }
  short8 taf[4][2];
  #pragma unroll
  for (int pt = 0; pt < 4; pt++)
    #pragma unroll
    for (int kc = 0; kc < 2; kc++)
      taf[pt][kc] = ld_g8(ta + (size_t)((pt*4 + wid)*16 + l16)*512 + n*64
                             + kc*32 + quad*8);
  __syncthreads();                    // c visible

  // ---- Main loop: pt-pair pipelined E -> T (dual Ew buffers)
  floatx4 Tacc[4][4];
  #pragma unroll
  for (int pt = 0; pt < 4; pt++)
    #pragma unroll
    for (int gt = 0; gt < 4; gt++) Tacc[pt][gt] = (floatx4){0.f, 0.f, 0.f, 0.f};
  float Zp = 0.f;
  char* bufA = smb + 34816 + wid * 2304;        // [16][72 B]
  char* bufB = bufA + 1152;
  for (int ch = 0; ch < nch; ch++) {
    const int qc = ch * 32;
    if (qc + 31 <= wid * 16) continue;  // all this wave's tiles dead
    short8 cfr[2][2];
    #pragma unroll
    for (int qt2 = 0; qt2 < 2; qt2++)
      #pragma unroll
      for (int kc = 0; kc < 2; kc++)
        cfr[qt2][kc] = *reinterpret_cast<const short8*>(
            smb + (qc + qt2*16 + l16)*136 + (kc*32 + quad*8)*2);
    short8 tef[4];
    #pragma unroll
    for (int gt = 0; gt < 4; gt++)
      tef[gt] = ld_g8(teT + (size_t)n*16384 + (gt*16 + l16)*256 + qc + quad*8);

    // pair (0,1): alive is a prefix (ptb increasing in pt)
    {
      const bool alive0 = ((0*4 + wid)*16 < qc + 31);
      const bool alive1 = ((1*4 + wid)*16 < qc + 31);
      short8 ef0, ef1;
      if (alive0) { E_PHASE(0, bufA)
                    ef0 = *reinterpret_cast<const short8*>(bufA + l16*72 + quad*16); }
      if (alive1) { E_PHASE(1, bufB)
                    ef1 = *reinterpret_cast<const short8*>(bufB + l16*72 + quad*16); }
      if (alive0) { __builtin_amdgcn_s_setprio(1);
        #pragma unroll
        for (int gt = 0; gt < 4; gt++) Tacc[0][gt] = mfma16(ef0, tef[gt], Tacc[0][gt]);
        __builtin_amdgcn_s_setprio(0); }
      if (alive1) { __builtin_amdgcn_s_setprio(1);
        #pragma unroll
        for (int gt = 0; gt < 4; gt++) Tacc[1][gt] = mfma16(ef1, tef[gt], Tacc[1][gt]);
        __builtin_amdgcn_s_setprio(0); }
    }
    // pair (2,3)
    {
      const bool alive2 = ((2*4 + wid)*16 < qc + 31);
      const bool alive3 = ((3*4 + wid)*16 < qc + 31);
      short8 ef2, ef3;
      if (alive2) { E_PHASE(2, bufA)
                    ef2 = *reinterpret_cast<const short8*>(bufA + l16*72 + quad*16); }
      if (alive3) { E_PHASE(3, bufB)
                    ef3 = *reinterpret_cast<const short8*>(bufB + l16*72 + quad*16); }
      if (alive2) { __builtin_amdgcn_s_setprio(1);
        #pragma unroll
        for (int gt = 0; gt < 4; gt++) Tacc[2][gt] = mfma16(ef2, tef[gt], Tacc[2][gt]);
        __builtin_amdgcn_s_setprio(0); }
      if (alive3) { __builtin_amdgcn_s_setprio(1);
        #pragma unroll
        for (int gt = 0; gt < 4; gt++) Tacc[3][gt] = mfma16(ef3, tef[gt], Tacc[3][gt]);
        __builtin_amdgcn_s_setprio(0); }
    }
  }
  #pragma unroll
  for (int off = 32; off; off >>= 1) Zp += __shfl_down(Zp, off);
  float* scr = reinterpret_cast<float*>(smb + 44032);
  if (lane == 0) scr[wid] = Zp;
  __syncthreads();                    // closes all c reads; Z visible
  const float rinv = 1.f / (scr[0] + scr[1] + scr[2] + scr[3]);

  // ---- Tt[g][p] over dead c region; skip p >= rcap
  #pragma unroll
  for (int pt = 0; pt < 4; pt++) {
    if ((pt*4 + wid)*16 >= rcap) continue;
    #pragma unroll
    for (int gt = 0; gt < 4; gt++)
      #pragma unroll
      for (int reg = 0; reg < 4; reg++) {
        int g = gt*16 + l16;
        int p = (pt*4 + wid)*16 + quad*4 + reg;
        *reinterpret_cast<bf16*>(smb + g*528 + p*2) = __float2bfloat16(Tacc[pt][gt][reg]);
      }
  }
  __syncthreads();

  // ---- S[g][h] = T^T·tdT (K capped at 32*nch); store S' = S*rinv
  {
    short8 Taf[8];
    #pragma unroll
    for (int kc = 0; kc < 8; kc++)
      if (kc < nch)
        Taf[kc] = *reinterpret_cast<const short8*>(
            smb + (wid*16 + l16)*528 + (kc*32 + quad*8)*2);
    #pragma unroll
    for (int ht = 0; ht < 4; ht++) {
      floatx4 acc = {0.f, 0.f, 0.f, 0.f};
      __builtin_amdgcn_s_setprio(1);
      #pragma unroll
      for (int kc = 0; kc < 8; kc++) {
        if (kc < nch) {
          short8 bfragd = ld_g8(tdT + (size_t)n*16384 + (ht*16 + l16)*256 + kc*32 + quad*8);
          acc = mfma16(Taf[kc], bfragd, acc);
        }
      }
      __builtin_amdgcn_s_setprio(0);
      #pragma unroll
      for (int reg = 0; reg < 4; reg++) {
        int g = wid*16 + quad*4 + reg, h = ht*16 + l16;
        srow[h*64 + g] = __float2bfloat16(acc[reg] * rinv);
      }
    }
  }
}

// ---------------- z_all: split-K z, 16-row tiles, wave-per-ft ---------------
// Grid (16, 8, ks). Per-thread ds_read_u16: 128; 1024 blocks @ks=8.
template<typename TW>
__device__ __forceinline__ void z_body(
    const bf16* __restrict__ Sbuf, const TW* __restrict__ WV,
    float* __restrict__ zpart, int kslice, char* lds)
{
  const int rt = blockIdx.x, n = blockIdx.y, ks = blockIdx.z;
  const int t = threadIdx.x, wid = t >> 6, lane = t & 63, quad = lane >> 4, l16 = lane & 15;
  const int rw = rt * 16;
  const int k0 = ks * kslice;
  const TW*  wvn = WV   + (size_t)n * 262144;
  const bf16* sn = Sbuf + (size_t)n * 1048576;
  floatx4 acc = {0.f, 0.f, 0.f, 0.f};
  const int row = t >> 3, f8 = (t & 7) * 8;
  for (int kb = k0; kb < k0 + kslice; kb += 32) {
    { const TW* src = wvn + (size_t)(kb + row) * 64 + f8;
      short sv[8];
      if constexpr (sizeof(TW) == 2) {
        short8 v = ld_g8((const bf16*)src);
        #pragma unroll
        for (int j = 0; j < 8; j++) sv[j] = v[j];
      } else {
        float4 a = *reinterpret_cast<const float4*>(src);
        float4 b = *reinterpret_cast<const float4*>(src + 4);
        sv[0]=bfs(a.x); sv[1]=bfs(a.y); sv[2]=bfs(a.z); sv[3]=bfs(a.w);
        sv[4]=bfs(b.x); sv[5]=bfs(b.y); sv[6]=bfs(b.z); sv[7]=bfs(b.w);
      }
      short* dst = reinterpret_cast<short*>(lds + row*136 + f8*2);
      s16x4 lo = {sv[0],sv[1],sv[2],sv[3]}, hi = {sv[4],sv[5],sv[6],sv[7]};
      *reinterpret_cast<s16x4*>(dst)     = lo;
      *reinterpret_cast<s16x4*>(dst + 4) = hi;
    }
    __syncthreads();
    short8 af = ld_g8(sn + (size_t)(rw + l16) * 4096 + kb + quad*8);
    short8 bfv;
    #pragma unroll
    for (int j = 0; j < 8; j++)
      bfv[j] = *reinterpret_cast<const short*>(
          lds + (quad*8 + j)*136 + (wid*16 + l16)*2);
    acc = mfma16(af, bfv, acc);
    __syncthreads();
  }
  float* zp = zpart + (size_t)ks * 131072;
  #pragma unroll
  for (int reg = 0; reg < 4; reg++)
    zp[(size_t)(rw + quad*4 + reg) * 512 + n*64 + wid*16 + l16] = acc[reg];
}

__global__ __launch_bounds__(256) void z_all(
    const void* __restrict__ x, const bf16* __restrict__ Sbuf,
    const void* __restrict__ WV, float* __restrict__ zpart, int kslice)
{
  __shared__ __align__(16) char lds[32 * 136];
  if (is_bf16_x(x)) z_body<bf16>(Sbuf, (const bf16*)WV, zpart, kslice, lds);
  else              z_body<float>(Sbuf, (const float*)WV, zpart, kslice, lds);
}

// ---------------- gemm_all: out = (sum_ks zpart) @ WO + bO, 32x32 tiles -----
// Grid (16, 8); zred folded: A-staging sums ks fp32 partials inline.
template<typename TB, typename TC>
__device__ __forceinline__ void gemm_body(
    const float* __restrict__ zp, int ks, const TB* __restrict__ B,
    TC* __restrict__ C, const TB* __restrict__ bias, float* As, float* Bs)
{
  const int m0 = blockIdx.y * 32, n0 = blockIdx.x * 32;
  const int t = threadIdx.x, tx = t & 15, ty = t >> 4;
  float acc[2][2] = {};
  for (int k0 = 0; k0 < 512; k0 += 16) {
    { int m = t >> 3, kk = (t & 7) * 2;
      size_t base = (size_t)(m0 + m) * 512 + (k0 + kk);
      float a0 = 0.f, a1 = 0.f;
      for (int k = 0; k < ks; k++) {
        float2 u = *reinterpret_cast<const float2*>(zp + (size_t)k*131072 + base);
        a0 += u.x; a1 += u.y;
      }
      As[(kk+0)*34+m] = a0; As[(kk+1)*34+m] = a1; }
    { int kk = t >> 4, nn = (t & 15) * 2;
      const TB* bp = B + (size_t)(k0 + kk) * 512 + (n0 + nn);
      Bs[kk*34+nn+0] = ldf(bp+0); Bs[kk*34+nn+1] = ldf(bp+1); }
    __syncthreads();
    #pragma unroll
    for (int kk = 0; kk < 16; kk++) {
      float a0 = As[kk*34 + ty*2], a1 = As[kk*34 + ty*2 + 1];
      float b0 = Bs[kk*34 + tx*2], b1 = Bs[kk*34 + tx*2 + 1];
      acc[0][0] += a0*b0; acc[0][1] += a0*b1;
      acc[1][0] += a1*b0; acc[1][1] += a1*b1;
    }
    __syncthreads();
  }
  #pragma unroll
  for (int im = 0; im < 2; im++) {
    TC* cp = C + (size_t)(m0 + ty*2 + im) * 512 + n0 + tx*2;
    #pragma unroll
    for (int in = 0; in < 2; in++) {
      float v = acc[im][in] + ldf(bias + n0 + tx*2 + in);
      stf(cp + in, v);
    }
  }
}

__global__ __launch_bounds__(256) void gemm_all(
    const void* __restrict__ x, const float* __restrict__ zpart, int ks,
    const void* __restrict__ WO, const void* __restrict__ bO,
    void* __restrict__ out)
{
  __shared__ float As[16*34];
  __shared__ float Bs[16*34];
  if (is_bf16_x(x))
    gemm_body<bf16, bf16>(zpart, ks, (const bf16*)WO, (bf16*)out,
                          (const bf16*)bO, As, Bs);
  else
    gemm_body<float, float>(zpart, ks, (const float*)WO, (float*)out,
                            (const float*)bO, As, Bs);
}

extern "C" void kernel_launch(void* const* d_in, const int* in_sizes, int n_in,
                              void* d_out, int out_size, void* d_ws, size_t ws_size,
                              hipStream_t stream)
{
  (void)in_sizes; (void)n_in; (void)out_size;
  // Workspace (round-16 layout):
  //   tproj bf16 [256, 1310976); tbsbf [1310976, 1343744)
  //   s1t bf16 [1343744, 3440896)
  //   Sbuf bf16 [4194304, 20971520); wkbf bf16 [4194304, 8388608) rides the
  //     dead-until-tri_attn Sbuf head (s1t completes before tri_attn).
  //   zpart fp32: ks=8 @ [20971520, 25165824) if ws allows, else ks=2 over
  //   dead s1t region [1343744, ...) (s1t dead after tri_attn).
  char* wsb = (char*)d_ws;
  bf16* tproj = (bf16*)(wsb + 256);
  bf16* tbsbf = (bf16*)(wsb + 1310976);
  bf16* s1t   = (bf16*)(wsb + 1343744);
  bf16* Sbuf  = (bf16*)(wsb + 4194304);
  bf16* wkbf  = (bf16*)(wsb + 4194304);
  const long TE = 131072;
  const bool bigws = (ws_size == 0) || (ws_size >= 25165824);
  const int  ks     = bigws ? 8 : 2;
  const int  kslice = 4096 / ks;
  float* zpart = (float*)(bigws ? (wsb + 20971520) : (wsb + 1343744));

  proj_all<<<dim3(1,4,64), 256, 0, stream>>>(
      d_in[0], d_in[1], d_in[2], d_in[3], d_in[4], d_in[5], d_in[6],
      d_in[7], d_in[8], d_in[9], d_in[10], tproj, d_in[12], wkbf);
  s1t_all<<<dim3(64,5), 256, 0, stream>>>(
      d_in[0], tproj + 1*TE, tproj + 2*TE, d_in[12], wkbf, tbsbf, s1t);
  tri_attn<<<2048, 256, 0, stream>>>(
      tproj, tbsbf, s1t, tproj + 3*TE, tproj + 4*TE, Sbuf);
  z_all<<<dim3(16,8,ks), 256, 0, stream>>>(
      d_in[0], Sbuf, d_in[11], zpart, kslice);
  gemm_all<<<dim3(16,8), 256, 0, stream>>>(
      d_in[0], zpart, ks, d_in[13], d_in[14], d_out);
}

// Round 14
// 237.283 us; speedup vs baseline: 1.1977x; 1.1977x over previous
//
#include <hip/hip_runtime.h>
#include <hip/hip_bf16.h>

// TrittentionCube on MI355X. B=1, P=256, D=512, N=8, H=64. Round 24:
//  - Recombination of verified pieces. vs round 19 (best, 244.9 us), ONE
//    bundle kept from r23: WK fp32->bf16 rider on proj_all's dispatch +
//    always-bf16 s1t_all (r23 profile attribution: this side saved ~8-11 us;
//    s1t sheds 1024 VALU cvts + half B-traffic per wave; rider ~free).
//  - r23's zred-fold REVERTED (it put an 8-deep serial dependent fp32 load
//    chain in gemm_all's A-staging at 0.5 blocks/CU: 78 us, MfmaUtil 0,
//    top-5 all gemm_all). Back to z_all ks=8 + zred + bf16-zbb gemm_all.
//  - tri_attn frozen at r19 form (65.4 us structural floor: r20 prefetch hit
//    the >128-VGPR wave cliff, r22 8-wave hit barrier/LDS contention).

typedef __hip_bfloat16 bf16;
typedef __attribute__((ext_vector_type(8))) short short8;
typedef __attribute__((ext_vector_type(4))) short s16x4;
typedef __attribute__((ext_vector_type(4))) float floatx4;

__device__ __forceinline__ float ldf(const float* p){ return *p; }
__device__ __forceinline__ float ldf(const bf16* p){ return __bfloat162float(*p); }
__device__ __forceinline__ void  stf(float* p, float v){ *p = v; }
__device__ __forceinline__ void  stf(bf16*  p, float v){ *p = __float2bfloat16(v); }

__device__ __forceinline__ floatx4 mfma16(short8 a, short8 b, floatx4 c){
  return __builtin_amdgcn_mfma_f32_16x16x32_bf16(a, b, c, 0, 0, 0);
}
__device__ __forceinline__ short8 ld_g8(const bf16* p){
  return *reinterpret_cast<const short8*>(p);
}
__device__ __forceinline__ short bfs(float x){
  bf16 v = __float2bfloat16(x);
  return *reinterpret_cast<short*>(&v);
}

// Vectorized 4-elem load -> fp32 (G13: no scalar bf16 staging).
__device__ __forceinline__ void ld4(const bf16* p, float* o){
  s16x4 v = *reinterpret_cast<const s16x4*>(p);
  #pragma unroll
  for (int i = 0; i < 4; i++)
    o[i] = __uint_as_float(((unsigned)(unsigned short)v[i]) << 16);
}
__device__ __forceinline__ void ld4(const float* p, float* o){
  float4 v = *reinterpret_cast<const float4*>(p);
  o[0] = v.x; o[1] = v.y; o[2] = v.z; o[3] = v.w;
}

// Wave-uniform dtype detect: threshold 40/64, >7 sigma from both dtypes.
__device__ __forceinline__ bool is_bf16_x(const void* xv)
{
  const unsigned* x32 = (const unsigned*)xv;
  unsigned w = x32[threadIdx.x & 63];
  unsigned lo = w & 0xFFFFu;
  unsigned e  = (lo >> 7) & 0xFFu;
  bool v = (lo == 0u) || (e >= 90u && e <= 145u);
  unsigned long long m = __ballot(v);
  return __popcll(m) >= 40;
}

// ---------------- proj_all (r19 body) + WK-convert rider (bz>=40) -----------
template<typename TI>
__device__ __forceinline__ void proj_body(
    const TI* __restrict__ x, const TI* const* Ws, const TI* const* bs,
    bf16* __restrict__ tproj, float* As, float* Bs)
{
  const int bz = blockIdx.z, j = bz >> 3, n = bz & 7;
  const TI* B    = Ws[j] + (size_t)n * 32768;
  const TI* bias = bs[j] + n * 64;
  bf16* out = tproj + (size_t)j * 131072;
  const int m0 = blockIdx.y * 64;
  const int t = threadIdx.x, tx = t & 15, ty = t >> 4;
  float acc[4][4] = {};
  for (int k0 = 0; k0 < 512; k0 += 16) {
    { int m = t >> 2, kk = (t & 3) * 4;
      float a[4]; ld4(x + (size_t)(m0 + m) * 512 + (k0 + kk), a);
      As[(kk+0)*68+m] = a[0]; As[(kk+1)*68+m] = a[1];
      As[(kk+2)*68+m] = a[2]; As[(kk+3)*68+m] = a[3]; }
    { int kk = t >> 4, nn = (t & 15) * 4;
      float b[4]; ld4(B + (size_t)(k0 + kk) * 64 + nn, b);
      Bs[kk*68+nn+0] = b[0]; Bs[kk*68+nn+1] = b[1];
      Bs[kk*68+nn+2] = b[2]; Bs[kk*68+nn+3] = b[3]; }
    __syncthreads();
    #pragma unroll
    for (int kk = 0; kk < 16; kk++) {
      float4 a4 = *reinterpret_cast<const float4*>(&As[kk*68 + ty*4]);
      float4 b4 = *reinterpret_cast<const float4*>(&Bs[kk*68 + tx*4]);
      float av[4] = {a4.x,a4.y,a4.z,a4.w}, bv[4] = {b4.x,b4.y,b4.z,b4.w};
      #pragma unroll
      for (int im = 0; im < 4; im++)
        #pragma unroll
        for (int in = 0; in < 4; in++) acc[im][in] += av[im] * bv[in];
    }
    __syncthreads();
  }
  #pragma unroll
  for (int im = 0; im < 4; im++)
    #pragma unroll
    for (int in = 0; in < 4; in++) {
      float v = acc[im][in] + ldf(bias + tx*4 + in);
      int p = m0 + ty*4 + im, h = tx*4 + in;
      if (j < 3) out[(size_t)p * 512 + n*64 + h] = __float2bfloat16(v);
      else       out[(size_t)n * 16384 + (size_t)h * 256 + p] = __float2bfloat16(v);
    }
}

__global__ __launch_bounds__(256) void proj_all(
    const void* __restrict__ x,
    const void* W0, const void* b0, const void* W1, const void* b1,
    const void* W2, const void* b2, const void* W3, const void* b3,
    const void* W4, const void* b4, bf16* __restrict__ tproj,
    const void* __restrict__ WKf, bf16* __restrict__ wkbf)
{
  __shared__ float As[16*68];
  __shared__ float Bs[16*68];
  const int bz = blockIdx.z;
  if (bz >= 40) {
    // WK fp32 -> bf16 rider: 96 blocks (bz 40..63 x y 0..3), grid-stride x8.
    // Identical rounding to the old on-the-fly bfs path.
    if (is_bf16_x(x)) return;        // bf16 inputs: WK used directly
    const float* src = (const float*)WKf;
    const int cb = (bz - 40) * 4 + blockIdx.y;          // 0..95
    for (size_t i = ((size_t)cb*256 + threadIdx.x)*8; i < 2097152;
         i += (size_t)96*256*8) {
      float4 u0 = *reinterpret_cast<const float4*>(src + i);
      float4 u1 = *reinterpret_cast<const float4*>(src + i + 4);
      s16x4 lo = {bfs(u0.x), bfs(u0.y), bfs(u0.z), bfs(u0.w)};
      s16x4 hi = {bfs(u1.x), bfs(u1.y), bfs(u1.z), bfs(u1.w)};
      *reinterpret_cast<s16x4*>(wkbf + i)     = lo;
      *reinterpret_cast<s16x4*>(wkbf + i + 4) = hi;
    }
    return;
  }
  if (is_bf16_x(x)) {
    const bf16* Ws[5] = {(const bf16*)W0,(const bf16*)W1,(const bf16*)W2,
                         (const bf16*)W3,(const bf16*)W4};
    const bf16* bs[5] = {(const bf16*)b0,(const bf16*)b1,(const bf16*)b2,
                         (const bf16*)b3,(const bf16*)b4};
    proj_body<bf16>((const bf16*)x, Ws, bs, tproj, As, Bs);
  } else {
    const float* Ws[5] = {(const float*)W0,(const float*)W1,(const float*)W2,
                          (const float*)W3,(const float*)W4};
    const float* bs[5] = {(const float*)b0,(const float*)b1,(const float*)b2,
                          (const float*)b3,(const float*)b4};
    proj_body<float>((const float*)x, Ws, bs, tproj, As, Bs);
  }
}

// ---------------- s1t_all: always-bf16 s1t MFMA + tbs (grid y==4) -----------
__device__ __forceinline__ void s1t_body(
    const bf16* __restrict__ tc, const bf16* __restrict__ WK,
    bf16* __restrict__ s1t)
{
  const int i = blockIdx.x;
  const int t = threadIdx.x, wid = t >> 6, lane = t & 63, quad = lane >> 4, l16 = lane & 15;
  const int rw = blockIdx.y * 64 + wid * 16;
  floatx4 acc[4];
  #pragma unroll
  for (int jt = 0; jt < 4; jt++) acc[jt] = (floatx4){0.f, 0.f, 0.f, 0.f};
  for (int kc = 0; kc < 16; kc++) {
    short8 af = ld_g8(tc + (size_t)(rw + l16) * 512 + kc*32 + quad*8);
    const int n = kc >> 1, kk = (kc & 1) * 32 + quad * 8;
    #pragma unroll
    for (int jt = 0; jt < 4; jt++) {
      short8 bf = ld_g8(WK + ((size_t)(n*64 + i) * 64 + jt*16 + l16) * 64 + kk);
      acc[jt] = mfma16(af, bf, acc[jt]);
    }
  }
  #pragma unroll
  for (int jt = 0; jt < 4; jt++)
    #pragma unroll
    for (int reg = 0; reg < 4; reg++)
      s1t[(size_t)(rw + quad*4 + reg) * 4096 + i*64 + jt*16 + l16] =
          __float2bfloat16(acc[jt][reg]);
}

__global__ __launch_bounds__(256) void s1t_all(
    const void* __restrict__ x, const bf16* __restrict__ tb,
    const bf16* __restrict__ tc, const void* __restrict__ WK_orig,
    const bf16* __restrict__ wkbf,
    bf16* __restrict__ tbsbf, bf16* __restrict__ s1t)
{
  if (blockIdx.y == 4) {              // tbs: tbs[q][j] = (1/64)*sum_n tb[q][n][j]
    int t = blockIdx.x * 256 + threadIdx.x;
    int q = t >> 6, j = t & 63;
    float s = 0.f;
    #pragma unroll
    for (int n = 0; n < 8; n++) s += ldf(tb + q*512 + n*64 + j);
    tbsbf[t] = __float2bfloat16(s * 0.015625f);
    return;
  }
  const bf16* wk = is_bf16_x(x) ? (const bf16*)WK_orig : wkbf;
  s1t_body(tc, wk, s1t);
}

// ---------------- tri_attn (round-19 verbatim: pair-pipelined E->T) ---------
// LDS 44544 B: [0,34816) c [256][136 B] / Tt [64][528 B]; [34816,44032) Ew
// 2 bufs x [16][72 B] x4 waves; [44032,44544) scr.
#define E_PHASE(PT, BUF)                                                      \
  {                                                                           \
    const int ptb_ = ((PT)*4 + wid) * 16;                                     \
    for (int qt2 = 0; qt2 < 2; qt2++) {                                       \
      const int qh = qc + qt2*16;                                             \
      char* erow0 = (BUF) + (quad*4)*72 + (qt2*16 + l16)*2;                   \
      if (qh + 15 <= ptb_) {                                                  \
        for (int reg = 0; reg < 4; reg++)                                     \
          *reinterpret_cast<bf16*>(erow0 + reg*72) = __float2bfloat16(0.f);   \
      } else {                                                                \
        floatx4 acc = {0.f, 0.f, 0.f, 0.f};                                   \
        acc = mfma16(taf[PT][0], cfr[qt2][0], acc);                           \
        acc = mfma16(taf[PT][1], cfr[qt2][1], acc);                           \
        if (qh >= ptb_ + 16 && qh + 15 < r) {                                 \
          for (int reg = 0; reg < 4; reg++) {                                 \
            float e = __expf(acc[reg]);                                       \
            Zp += e;                                                          \
            *reinterpret_cast<bf16*>(erow0 + reg*72) = __float2bfloat16(e);   \
          }                                                                   \
        } else {                                                              \
          for (int reg = 0; reg < 4; reg++) {                                 \
            int p = ptb_ + quad*4 + reg;                                      \
            int q = qh + l16;                                                 \
            float e = (p < q && q < r) ? __expf(acc[reg]) : 0.f;              \
            Zp += e;                                                          \
            *reinterpret_cast<bf16*>(erow0 + reg*72) = __float2bfloat16(e);   \
          }                                                                   \
        }                                                                     \
      }                                                                       \
    }                                                                         \
  }

__global__ __launch_bounds__(256) void tri_attn(
    const bf16* __restrict__ ta,     // [p][n*64+h]
    const bf16* __restrict__ tbsbf,  // [q][64]
    const bf16* __restrict__ s1t,    // [r][i*64+j]
    const bf16* __restrict__ tdT,    // [n][h][p]
    const bf16* __restrict__ teT,    // [n][g][q]
    bf16* __restrict__ Sbuf)         // [n][r][h*64+g]
{
  __shared__ __align__(16) char smb[44544];
  const int bx = blockIdx.x;
  const int n = bx & 7;               // n -> XCD affinity
  const int r = 255 - (bx >> 3);      // big-r first
  const int t = threadIdx.x;
  const int wid = t >> 6, lane = t & 63, quad = lane >> 4, l16 = lane & 15;
  bf16* srow = Sbuf + (size_t)n * 1048576 + (size_t)r * 4096;
  if (r < 2) {                        // no valid (p<q<r): S' = 0
    short8 zz = (short8){0,0,0,0,0,0,0,0};
    reinterpret_cast<short8*>(srow)[t]       = zz;
    reinterpret_cast<short8*>(srow)[t + 256] = zz;
    return;
  }
  const int nch  = ((r - 1) >> 5) + 1;
  const int rcap = nch * 32;

  // ---- Phase 1: c[q][i] = tbs[q,:]·s1t[r][i,:]
  {
    const bf16* s1r = s1t + (size_t)r * 4096;
    short8 bfr[4][2];
    #pragma unroll
    for (int it = 0; it < 4; it++)
      #pragma unroll
      for (int kc = 0; kc < 2; kc++)
        bfr[it][kc] = ld_g8(s1r + (it*16 + l16)*64 + kc*32 + quad*8);
    #pragma unroll
    for (int qt = 0; qt < 4; qt++) {
      const int q0 = wid * 64 + qt * 16;
      if (q0 >= rcap) continue;
      if (q0 >= r) {
        #pragma unroll
        for (int it = 0; it < 4; it++)
          #pragma unroll
          for (int reg = 0; reg < 4; reg++) {
            int q = q0 + quad*4 + reg;
            *reinterpret_cast<bf16*>(smb + q*136 + (it*16 + l16)*2) =
                __float2bfloat16(0.f);
          }
        continue;
      }
      short8 af0 = ld_g8(tbsbf + (q0 + l16)*64 + quad*8);
      short8 af1 = ld_g8(tbsbf + (q0 + l16)*64 + 32 + quad*8);
      #pragma unroll
      for (int it = 0; it < 4; it++) {
        floatx4 acc = {0.f, 0.f, 0.f, 0.f};
        acc = mfma16(af0, bfr[it][0], acc);
        acc = mfma16(af1, bfr[it][1], acc);
        #pragma unroll
        for (int reg = 0; reg < 4; reg++) {
          int q = q0 + quad*4 + reg;
          float v = (q >= 1 && q < r) ? acc[reg] : 0.f;
          *reinterpret_cast<bf16*>(smb + q*136 + (it*16 + l16)*2) = __float2bfloat16(v);
        }
      }
    }
  }
  short8 taf[4][2];
  #pragma unroll
  for (int pt = 0; pt < 4; pt++)
    #pragma unroll
    for (int kc = 0; kc < 2; kc++)
      taf[pt][kc] = ld_g8(ta + (size_t)((pt*4 + wid)*16 + l16)*512 + n*64
                             + kc*32 + quad*8);
  __syncthreads();                    // c visible

  // ---- Main loop: pt-pair pipelined E -> T (dual Ew buffers)
  floatx4 Tacc[4][4];
  #pragma unroll
  for (int pt = 0; pt < 4; pt++)
    #pragma unroll
    for (int gt = 0; gt < 4; gt++) Tacc[pt][gt] = (floatx4){0.f, 0.f, 0.f, 0.f};
  float Zp = 0.f;
  char* bufA = smb + 34816 + wid * 2304;        // [16][72 B]
  char* bufB = bufA + 1152;
  for (int ch = 0; ch < nch; ch++) {
    const int qc = ch * 32;
    if (qc + 31 <= wid * 16) continue;  // all this wave's tiles dead
    short8 cfr[2][2];
    #pragma unroll
    for (int qt2 = 0; qt2 < 2; qt2++)
      #pragma unroll
      for (int kc = 0; kc < 2; kc++)
        cfr[qt2][kc] = *reinterpret_cast<const short8*>(
            smb + (qc + qt2*16 + l16)*136 + (kc*32 + quad*8)*2);
    short8 tef[4];
    #pragma unroll
    for (int gt = 0; gt < 4; gt++)
      tef[gt] = ld_g8(teT + (size_t)n*16384 + (gt*16 + l16)*256 + qc + quad*8);

    // pair (0,1): alive is a prefix (ptb increasing in pt)
    {
      const bool alive0 = ((0*4 + wid)*16 < qc + 31);
      const bool alive1 = ((1*4 + wid)*16 < qc + 31);
      short8 ef0, ef1;
      if (alive0) { E_PHASE(0, bufA)
                    ef0 = *reinterpret_cast<const short8*>(bufA + l16*72 + quad*16); }
      if (alive1) { E_PHASE(1, bufB)
                    ef1 = *reinterpret_cast<const short8*>(bufB + l16*72 + quad*16); }
      if (alive0) { __builtin_amdgcn_s_setprio(1);
        #pragma unroll
        for (int gt = 0; gt < 4; gt++) Tacc[0][gt] = mfma16(ef0, tef[gt], Tacc[0][gt]);
        __builtin_amdgcn_s_setprio(0); }
      if (alive1) { __builtin_amdgcn_s_setprio(1);
        #pragma unroll
        for (int gt = 0; gt < 4; gt++) Tacc[1][gt] = mfma16(ef1, tef[gt], Tacc[1][gt]);
        __builtin_amdgcn_s_setprio(0); }
    }
    // pair (2,3)
    {
      const bool alive2 = ((2*4 + wid)*16 < qc + 31);
      const bool alive3 = ((3*4 + wid)*16 < qc + 31);
      short8 ef2, ef3;
      if (alive2) { E_PHASE(2, bufA)
                    ef2 = *reinterpret_cast<const short8*>(bufA + l16*72 + quad*16); }
      if (alive3) { E_PHASE(3, bufB)
                    ef3 = *reinterpret_cast<const short8*>(bufB + l16*72 + quad*16); }
      if (alive2) { __builtin_amdgcn_s_setprio(1);
        #pragma unroll
        for (int gt = 0; gt < 4; gt++) Tacc[2][gt] = mfma16(ef2, tef[gt], Tacc[2][gt]);
        __builtin_amdgcn_s_setprio(0); }
      if (alive3) { __builtin_amdgcn_s_setprio(1);
        #pragma unroll
        for (int gt = 0; gt < 4; gt++) Tacc[3][gt] = mfma16(ef3, tef[gt], Tacc[3][gt]);
        __builtin_amdgcn_s_setprio(0); }
    }
  }
  #pragma unroll
  for (int off = 32; off; off >>= 1) Zp += __shfl_down(Zp, off);
  float* scr = reinterpret_cast<float*>(smb + 44032);
  if (lane == 0) scr[wid] = Zp;
  __syncthreads();                    // closes all c reads; Z visible
  const float rinv = 1.f / (scr[0] + scr[1] + scr[2] + scr[3]);

  // ---- Tt[g][p] over dead c region; skip p >= rcap
  #pragma unroll
  for (int pt = 0; pt < 4; pt++) {
    if ((pt*4 + wid)*16 >= rcap) continue;
    #pragma unroll
    for (int gt = 0; gt < 4; gt++)
      #pragma unroll
      for (int reg = 0; reg < 4; reg++) {
        int g = gt*16 + l16;
        int p = (pt*4 + wid)*16 + quad*4 + reg;
        *reinterpret_cast<bf16*>(smb + g*528 + p*2) = __float2bfloat16(Tacc[pt][gt][reg]);
      }
  }
  __syncthreads();

  // ---- S[g][h] = T^T·tdT (K capped at 32*nch); store S' = S*rinv
  {
    short8 Taf[8];
    #pragma unroll
    for (int kc = 0; kc < 8; kc++)
      if (kc < nch)
        Taf[kc] = *reinterpret_cast<const short8*>(
            smb + (wid*16 + l16)*528 + (kc*32 + quad*8)*2);
    #pragma unroll
    for (int ht = 0; ht < 4; ht++) {
      floatx4 acc = {0.f, 0.f, 0.f, 0.f};
      __builtin_amdgcn_s_setprio(1);
      #pragma unroll
      for (int kc = 0; kc < 8; kc++) {
        if (kc < nch) {
          short8 bfragd = ld_g8(tdT + (size_t)n*16384 + (ht*16 + l16)*256 + kc*32 + quad*8);
          acc = mfma16(Taf[kc], bfragd, acc);
        }
      }
      __builtin_amdgcn_s_setprio(0);
      #pragma unroll
      for (int reg = 0; reg < 4; reg++) {
        int g = wid*16 + quad*4 + reg, h = ht*16 + l16;
        srow[h*64 + g] = __float2bfloat16(acc[reg] * rinv);
      }
    }
  }
}

// ---------------- z_all: split-K z, 16-row tiles, wave-per-ft ---------------
// Grid (16, 8, ks). Per-thread ds_read_u16: 128; 1024 blocks @ks=8.
template<typename TW>
__device__ __forceinline__ void z_body(
    const bf16* __restrict__ Sbuf, const TW* __restrict__ WV,
    float* __restrict__ zpart, int kslice, char* lds)
{
  const int rt = blockIdx.x, n = blockIdx.y, ks = blockIdx.z;
  const int t = threadIdx.x, wid = t >> 6, lane = t & 63, quad = lane >> 4, l16 = lane & 15;
  const int rw = rt * 16;
  const int k0 = ks * kslice;
  const TW*  wvn = WV   + (size_t)n * 262144;
  const bf16* sn = Sbuf + (size_t)n * 1048576;
  floatx4 acc = {0.f, 0.f, 0.f, 0.f};
  const int row = t >> 3, f8 = (t & 7) * 8;
  for (int kb = k0; kb < k0 + kslice; kb += 32) {
    { const TW* src = wvn + (size_t)(kb + row) * 64 + f8;
      short sv[8];
      if constexpr (sizeof(TW) == 2) {
        short8 v = ld_g8((const bf16*)src);
        #pragma unroll
        for (int j = 0; j < 8; j++) sv[j] = v[j];
      } else {
        float4 a = *reinterpret_cast<const float4*>(src);
        float4 b = *reinterpret_cast<const float4*>(src + 4);
        sv[0]=bfs(a.x); sv[1]=bfs(a.y); sv[2]=bfs(a.z); sv[3]=bfs(a.w);
        sv[4]=bfs(b.x); sv[5]=bfs(b.y); sv[6]=bfs(b.z); sv[7]=bfs(b.w);
      }
      short* dst = reinterpret_cast<short*>(lds + row*136 + f8*2);
      s16x4 lo = {sv[0],sv[1],sv[2],sv[3]}, hi = {sv[4],sv[5],sv[6],sv[7]};
      *reinterpret_cast<s16x4*>(dst)     = lo;
      *reinterpret_cast<s16x4*>(dst + 4) = hi;
    }
    __syncthreads();
    short8 af = ld_g8(sn + (size_t)(rw + l16) * 4096 + kb + quad*8);
    short8 bfv;
    #pragma unroll
    for (int j = 0; j < 8; j++)
      bfv[j] = *reinterpret_cast<const short*>(
          lds + (quad*8 + j)*136 + (wid*16 + l16)*2);
    acc = mfma16(af, bfv, acc);
    __syncthreads();
  }
  float* zp = zpart + (size_t)ks * 131072;
  #pragma unroll
  for (int reg = 0; reg < 4; reg++)
    zp[(size_t)(rw + quad*4 + reg) * 512 + n*64 + wid*16 + l16] = acc[reg];
}

__global__ __launch_bounds__(256) void z_all(
    const void* __restrict__ x, const bf16* __restrict__ Sbuf,
    const void* __restrict__ WV, float* __restrict__ zpart, int kslice)
{
  __shared__ __align__(16) char lds[32 * 136];
  if (is_bf16_x(x)) z_body<bf16>(Sbuf, (const bf16*)WV, zpart, kslice, lds);
  else              z_body<float>(Sbuf, (const float*)WV, zpart, kslice, lds);
}

// zred: zbb[idx] = bf16( sum_ks zpart[ks][idx] ), idx over 256*512.
__global__ __launch_bounds__(256) void zred_kern(
    const float* __restrict__ zpart, bf16* __restrict__ zbb, int ks)
{
  int idx = blockIdx.x * 256 + threadIdx.x;   // 512 blocks
  float s = 0.f;
  for (int k = 0; k < ks; k++) s += zpart[(size_t)k * 131072 + idx];
  zbb[idx] = __float2bfloat16(s);
}

// ---------------- gemm_all: out = zbb @ WO + bO, 32x32 tiles ----------------
// Grid (16, 8) = 128 blocks; 2x2 accum/thread.
template<typename TB, typename TC>
__device__ __forceinline__ void gemm_body(
    const bf16* __restrict__ A, const TB* __restrict__ B, TC* __restrict__ C,
    const TB* __restrict__ bias, float* As, float* Bs)   // [16][34] each
{
  const int m0 = blockIdx.y * 32, n0 = blockIdx.x * 32;
  const int t = threadIdx.x, tx = t & 15, ty = t >> 4;
  float acc[2][2] = {};
  for (int k0 = 0; k0 < 512; k0 += 16) {
    { int m = t >> 3, kk = (t & 7) * 2;
      const bf16* ap = A + (size_t)(m0 + m) * 512 + (k0 + kk);
      As[(kk+0)*34+m] = ldf(ap+0); As[(kk+1)*34+m] = ldf(ap+1); }
    { int kk = t >> 4, nn = (t & 15) * 2;
      const TB* bp = B + (size_t)(k0 + kk) * 512 + (n0 + nn);
      Bs[kk*34+nn+0] = ldf(bp+0); Bs[kk*34+nn+1] = ldf(bp+1); }
    __syncthreads();
    #pragma unroll
    for (int kk = 0; kk < 16; kk++) {
      float a0 = As[kk*34 + ty*2], a1 = As[kk*34 + ty*2 + 1];
      float b0 = Bs[kk*34 + tx*2], b1 = Bs[kk*34 + tx*2 + 1];
      acc[0][0] += a0*b0; acc[0][1] += a0*b1;
      acc[1][0] += a1*b0; acc[1][1] += a1*b1;
    }
    __syncthreads();
  }
  #pragma unroll
  for (int im = 0; im < 2; im++) {
    TC* cp = C + (size_t)(m0 + ty*2 + im) * 512 + n0 + tx*2;
    #pragma unroll
    for (int in = 0; in < 2; in++) {
      float v = acc[im][in] + ldf(bias + n0 + tx*2 + in);
      stf(cp + in, v);
    }
  }
}

__global__ __launch_bounds__(256) void gemm_all(
    const void* __restrict__ x, const bf16* __restrict__ zbb,
    const void* __restrict__ WO, const void* __restrict__ bO,
    void* __restrict__ out)
{
  __shared__ float As[16*34];
  __shared__ float Bs[16*34];
  if (is_bf16_x(x))
    gemm_body<bf16, bf16>(zbb, (const bf16*)WO, (bf16*)out, (const bf16*)bO, As, Bs);
  else
    gemm_body<float, float>(zbb, (const float*)WO, (float*)out, (const float*)bO, As, Bs);
}

extern "C" void kernel_launch(void* const* d_in, const int* in_sizes, int n_in,
                              void* d_out, int out_size, void* d_ws, size_t ws_size,
                              hipStream_t stream)
{
  (void)in_sizes; (void)n_in; (void)out_size;
  // Workspace (round-16 layout):
  //   tproj bf16 [256, 1310976); tbsbf [1310976, 1343744)
  //   s1t bf16 [1343744, 3440896); zbb bf16 [3440896, 3703040)
  //   Sbuf bf16 [4194304, 20971520); wkbf bf16 [4194304, 8388608) rides the
  //     dead-until-tri_attn Sbuf head (s1t completes before tri_attn).
  //   zpart fp32: ks=8 @ [20971520, 25165824) if ws allows, else ks=2 over
  //   dead s1t region [1343744, ...) (s1t dead after tri_attn).
  char* wsb = (char*)d_ws;
  bf16* tproj = (bf16*)(wsb + 256);
  bf16* tbsbf = (bf16*)(wsb + 1310976);
  bf16* s1t   = (bf16*)(wsb + 1343744);
  bf16* zbb   = (bf16*)(wsb + 3440896);
  bf16* Sbuf  = (bf16*)(wsb + 4194304);
  bf16* wkbf  = (bf16*)(wsb + 4194304);
  const long TE = 131072;
  const bool bigws = (ws_size == 0) || (ws_size >= 25165824);
  const int  ks     = bigws ? 8 : 2;
  const int  kslice = 4096 / ks;
  float* zpart = (float*)(bigws ? (wsb + 20971520) : (wsb + 1343744));

  proj_all<<<dim3(1,4,64), 256, 0, stream>>>(
      d_in[0], d_in[1], d_in[2], d_in[3], d_in[4], d_in[5], d_in[6],
      d_in[7], d_in[8], d_in[9], d_in[10], tproj, d_in[12], wkbf);
  s1t_all<<<dim3(64,5), 256, 0, stream>>>(
      d_in[0], tproj + 1*TE, tproj + 2*TE, d_in[12], wkbf, tbsbf, s1t);
  tri_attn<<<2048, 256, 0, stream>>>(
      tproj, tbsbf, s1t, tproj + 3*TE, tproj + 4*TE, Sbuf);
  z_all<<<dim3(16,8,ks), 256, 0, stream>>>(
      d_in[0], Sbuf, d_in[11], zpart, kslice);
  zred_kern<<<512, 256, 0, stream>>>(zpart, zbb, ks);
  gemm_all<<<dim3(16,8), 256, 0, stream>>>(
      d_in[0], zbb, d_in[13], d_in[14], d_out);
}